// Round 8
// baseline (414.197 us; speedup 1.0000x reference)
//
#include <hip/hip_runtime.h>
#include <hip/hip_bf16.h>

// B=8192, N=M=K=2048, H=10.
// Pipeline (4 launches):
//   1) pre_kernel: fused [col-sum partials] + [row sums] + [X -> Xh,Xl bf16 split]
//   2) nca_update: finish col sums inline, per-cell MLP, write TRANSPOSED bf16
//      split Bth/Btl [M][N]
//   3) 3-term bf16 MFMA GEMM, 128x256 block / 64x128 per wave (32x32x16),
//      REGISTER-prefetch double-buffer + raw s_barrier (no vmcnt drain),
//      conflict-free swizzled LDS.
//   4) row softmax, one WAVE per row (no LDS, no barriers)

typedef short short8 __attribute__((ext_vector_type(8)));
typedef float floatx16 __attribute__((ext_vector_type(16)));

#define GK 2048
#define NROWS 2048
#define MCOLS 2048
#define NCHUNK 16

__device__ inline unsigned short f2bf_rne(float x) {
  unsigned u = __float_as_uint(x);
  unsigned r = (u + 0x7fffu + ((u >> 16) & 1u)) >> 16;
  return (unsigned short)r;
}
__device__ inline float bf2f(unsigned short h) {
  return __uint_as_float(((unsigned)h) << 16);
}

// ---------------- fused pre-pass --------------------------------------------
#define CS_BLOCKS 128
#define RS_BLOCKS 2048
__global__ __launch_bounds__(256) void pre_kernel(
    const float* __restrict__ X, const float* __restrict__ W,
    unsigned short* __restrict__ Xh, unsigned short* __restrict__ Xl,
    float* __restrict__ part, float* __restrict__ rowS) {
  const int bid = blockIdx.x;
  const int tid = threadIdx.x;

  if (bid < CS_BLOCKS) {
    int chunk = bid >> 3;                 // 0..15
    int j = (bid & 7) * 256 + tid;        // column
    int i0 = chunk * (NROWS / NCHUNK);
    float s = 0.f;
    for (int i = i0; i < i0 + NROWS / NCHUNK; ++i) s += W[(size_t)i * MCOLS + j];
    part[(size_t)chunk * MCOLS + j] = s;
  } else if (bid < CS_BLOCKS + RS_BLOCKS) {
    int row = bid - CS_BLOCKS;
    const float4* p = (const float4*)(W + (size_t)row * MCOLS);
    float4 a = p[tid];
    float4 b = p[tid + 256];
    float v = (a.x + a.y) + (a.z + a.w) + (b.x + b.y) + (b.z + b.w);
    __shared__ float red[256];
    red[tid] = v;
    __syncthreads();
    for (int s = 128; s > 0; s >>= 1) {
      if (tid < s) red[tid] += red[tid + s];
      __syncthreads();
    }
    if (tid == 0) rowS[row] = red[0];
  } else {
    size_t i = (size_t)(bid - CS_BLOCKS - RS_BLOCKS) * 256 + tid;
    float4 v = ((const float4*)X)[i];
    ushort4 h, l;
    h.x = f2bf_rne(v.x); l.x = f2bf_rne(v.x - bf2f(h.x));
    h.y = f2bf_rne(v.y); l.y = f2bf_rne(v.y - bf2f(h.y));
    h.z = f2bf_rne(v.z); l.z = f2bf_rne(v.z - bf2f(h.z));
    h.w = f2bf_rne(v.w); l.w = f2bf_rne(v.w - bf2f(h.w));
    ((ushort4*)Xh)[i] = h;
    ((ushort4*)Xl)[i] = l;
  }
}

// ------- NCA MLP -> new_weight, transposed bf16 split out -------------------
__global__ __launch_bounds__(256) void nca_update_kernel(
    const float* __restrict__ W, const float* __restrict__ part,
    const float* __restrict__ rowS,
    const float* __restrict__ W1, const float* __restrict__ b1,
    const float* __restrict__ W2, const float* __restrict__ b2,
    const float* __restrict__ W3, const float* __restrict__ b3,
    unsigned short* __restrict__ Bth, unsigned short* __restrict__ Btl) {
  __shared__ float sW1[30], sb1[10], sW2[100], sb2[10], sW3[10], sb3;
  __shared__ float sColS[32];
  __shared__ float cred[NCHUNK][33];
  __shared__ unsigned short Th[32][33], Tl[32][33];
  const int tid = threadIdx.x;
  const int i0 = blockIdx.y * 32;
  const int j0 = blockIdx.x * 32;

  if (tid < 30) sW1[tid] = W1[tid];
  if (tid < 10) { sb1[tid] = b1[tid]; sb2[tid] = b2[tid]; sW3[tid] = W3[tid]; }
  if (tid >= 32 && tid < 132) sW2[tid - 32] = W2[tid - 32];
  if (tid == 0) sb3 = b3[0];

  {
    int ch = tid >> 5;
    int jl = tid & 31;
    cred[ch][jl]     = part[(size_t)ch * MCOLS + j0 + jl];
    cred[ch + 8][jl] = part[(size_t)(ch + 8) * MCOLS + j0 + jl];
  }
  __syncthreads();
  if (tid < 32) {
    float s = 0.f;
#pragma unroll
    for (int c = 0; c < NCHUNK; ++c) s += cred[c][tid];
    sColS[tid] = s;
  }
  __syncthreads();

  const int r = tid >> 5;
  const int c = tid & 31;

  float w[4], fwd[4], bwd[4];
#pragma unroll
  for (int cell = 0; cell < 4; ++cell) {
    int il = r + 8 * cell;
    float wv = W[(size_t)(i0 + il) * MCOLS + j0 + c];
    w[cell] = wv;
    fwd[cell] = (sColS[c] - wv) * (1.0f / (float)(NROWS - 1));
    bwd[cell] = (rowS[i0 + il] - wv) * (1.0f / (float)(MCOLS - 1));
  }

  float h1[4][10];
#pragma unroll
  for (int o = 0; o < 10; ++o) {
    float w1a = sW1[o], w1b = sW1[10 + o], w1c = sW1[20 + o], bb = sb1[o];
#pragma unroll
    for (int cell = 0; cell < 4; ++cell) {
      float v = fmaf(w[cell], w1a, fmaf(fwd[cell], w1b, fmaf(bwd[cell], w1c, bb)));
      h1[cell][o] = fmaxf(v, 0.f);
    }
  }
  float u[4] = {sb3, sb3, sb3, sb3};
#pragma unroll
  for (int o = 0; o < 10; ++o) {
    float h2[4];
    float bb = sb2[o];
#pragma unroll
    for (int cell = 0; cell < 4; ++cell) h2[cell] = bb;
#pragma unroll
    for (int p = 0; p < 10; ++p) {
      float wv = sW2[p * 10 + o];
#pragma unroll
      for (int cell = 0; cell < 4; ++cell) h2[cell] = fmaf(h1[cell][p], wv, h2[cell]);
    }
    float w3 = sW3[o];
#pragma unroll
    for (int cell = 0; cell < 4; ++cell) u[cell] = fmaf(fmaxf(h2[cell], 0.f), w3, u[cell]);
  }

#pragma unroll
  for (int cell = 0; cell < 4; ++cell) {
    int il = r + 8 * cell;
    float nw = w[cell] + u[cell];
    unsigned short hb = f2bf_rne(nw);
    Th[il][c] = hb;
    Tl[il][c] = f2bf_rne(nw - bf2f(hb));
  }
  __syncthreads();

  {
    int r2 = tid >> 4;          // 0..15
    int ic = (tid & 15) * 2;    // 0..30
#pragma unroll
    for (int half = 0; half < 2; ++half) {
      int jl = r2 + 16 * half;
      ushort2 vh, vl;
      vh.x = Th[ic][jl];     vh.y = Th[ic + 1][jl];
      vl.x = Tl[ic][jl];     vl.y = Tl[ic + 1][jl];
      size_t oidx = (size_t)(j0 + jl) * NROWS + i0 + ic;
      *(ushort2*)(&Bth[oidx]) = vh;
      *(ushort2*)(&Btl[oidx]) = vl;
    }
  }
}

// ---------------- 3-term bf16 MFMA GEMM -------------------------------------
// Block tile 128(M) x 256(N), 4 waves, each wave 64x128 via 2x4 of 32x32x16.
// BK=16. LDS (24KB, shorts): Ah@0 Al@2048 Bh@4096 Bl@8192; each array split in
// 32-row blocks of 512 shorts; slot(row rl, chunk c) = 2*rl + (c ^ ((rl>>2)&1))
// -> 8-lane phases hit 8 distinct bank groups for BOTH writes and frag reads.
// Register prefetch: 6 float4 loads for tile i+1 issued before tile i's
// compute; only the ds_writes (after raw barrier #1) wait on them.
__global__ __launch_bounds__(256, 2) void gemm_kernel(
    const unsigned short* __restrict__ Xh, const unsigned short* __restrict__ Xl,
    const unsigned short* __restrict__ Bth, const unsigned short* __restrict__ Btl,
    float* __restrict__ C) {
  __shared__ __align__(16) short sLDS[12288];   // 24 KB

  const int tid = threadIdx.x;
  const int lane = tid & 63;
  const int wave = tid >> 6;
  const int wr = wave >> 1;    // 0..1 : 64-row half
  const int wc = wave & 1;     // 0..1 : 128-col half

  const int bx = blockIdx.x;   // 0..7   (256-col tiles)
  const int by = blockIdx.y;   // 0..63  (128-row tiles)

  // global staging bases (uniform)
  const unsigned short* g0 = Xh  + (size_t)(by * 128) * GK;        // A_h rows 0..127
  const unsigned short* g1 = Xl  + (size_t)(by * 128) * GK;        // A_l
  const unsigned short* g2 = Bth + (size_t)(bx * 256) * GK;        // B_h rows 0..127
  const unsigned short* g3 = g2 + 128 * GK;                        // B_h rows 128..255
  const unsigned short* g4 = Btl + (size_t)(bx * 256) * GK;        // B_l rows 0..127
  const unsigned short* g5 = g4 + 128 * GK;                        // B_l rows 128..255

  // per-thread staging offsets: thread t -> row r=t>>1, chunk c=t&1 (16B)
  const int voff = (tid >> 1) * GK + (tid & 1) * 8;                // shorts
  const int rl_ = (tid >> 1) & 31;
  const int waddr = ((tid >> 1) >> 5) * 512 +
                    (2 * rl_ + ((tid & 1) ^ ((rl_ >> 2) & 1))) * 8; // shorts

  // fragment read address: lane needs row m=lane&31, chunk=lane>>5
  const int m_ = lane & 31;
  const int fa = (2 * m_ + ((lane >> 5) ^ ((m_ >> 2) & 1))) * 8;   // shorts

  floatx16 acc[2][4];
#pragma unroll
  for (int i = 0; i < 2; ++i)
#pragma unroll
    for (int j = 0; j < 4; ++j)
#pragma unroll
      for (int e = 0; e < 16; ++e) acc[i][j][e] = 0.f;

  // ---- prologue: stage tile 0 ----
  {
    float4 q0 = *(const float4*)(g0 + voff);
    float4 q1 = *(const float4*)(g1 + voff);
    float4 q2 = *(const float4*)(g2 + voff);
    float4 q3 = *(const float4*)(g3 + voff);
    float4 q4 = *(const float4*)(g4 + voff);
    float4 q5 = *(const float4*)(g5 + voff);
    *(float4*)(sLDS + 0     + waddr) = q0;
    *(float4*)(sLDS + 2048  + waddr) = q1;
    *(float4*)(sLDS + 4096  + waddr) = q2;
    *(float4*)(sLDS + 6144  + waddr) = q3;
    *(float4*)(sLDS + 8192  + waddr) = q4;
    *(float4*)(sLDS + 10240 + waddr) = q5;
    __builtin_amdgcn_s_waitcnt(0xC07F);   // lgkmcnt(0)
    __builtin_amdgcn_s_barrier();
  }

  for (int it = 0; it < 128; ++it) {
    const int k = it * 16;  // shorts
    float4 p0, p1, p2, p3, p4, p5;
    const bool pre = (it < 127);
    if (pre) {
      const int kn = k + 16;
      p0 = *(const float4*)(g0 + voff + kn);
      p1 = *(const float4*)(g1 + voff + kn);
      p2 = *(const float4*)(g2 + voff + kn);
      p3 = *(const float4*)(g3 + voff + kn);
      p4 = *(const float4*)(g4 + voff + kn);
      p5 = *(const float4*)(g5 + voff + kn);
    }

    // fragments + MFMA (reads LDS tile `it`)
    short8 ah[2], al[2];
#pragma unroll
    for (int mi = 0; mi < 2; ++mi) {
      int base = (wr * 2 + mi) * 512 + fa;
      ah[mi] = *(const short8*)(sLDS + 0    + base);
      al[mi] = *(const short8*)(sLDS + 2048 + base);
    }
#pragma unroll
    for (int ni = 0; ni < 4; ++ni) {
      int base = (wc * 4 + ni) * 512 + fa;
      short8 bh = *(const short8*)(sLDS + 4096 + base);
      short8 bl = *(const short8*)(sLDS + 8192 + base);
#pragma unroll
      for (int mi = 0; mi < 2; ++mi) {
        acc[mi][ni] = __builtin_amdgcn_mfma_f32_32x32x16_bf16(ah[mi], bh, acc[mi][ni], 0, 0, 0);
        acc[mi][ni] = __builtin_amdgcn_mfma_f32_32x32x16_bf16(al[mi], bh, acc[mi][ni], 0, 0, 0);
        acc[mi][ni] = __builtin_amdgcn_mfma_f32_32x32x16_bf16(ah[mi], bl, acc[mi][ni], 0, 0, 0);
      }
    }

    __builtin_amdgcn_s_waitcnt(0xC07F);   // my ds_reads done
    __builtin_amdgcn_s_barrier();          // all waves done reading tile `it`
    if (pre) {
      *(float4*)(sLDS + 0     + waddr) = p0;   // compiler waits vmcnt as needed
      *(float4*)(sLDS + 2048  + waddr) = p1;
      *(float4*)(sLDS + 4096  + waddr) = p2;
      *(float4*)(sLDS + 6144  + waddr) = p3;
      *(float4*)(sLDS + 8192  + waddr) = p4;
      *(float4*)(sLDS + 10240 + waddr) = p5;
      __builtin_amdgcn_s_waitcnt(0xC07F); // writes complete
    }
    __builtin_amdgcn_s_barrier();          // tile `it+1` visible to all
  }

  // epilogue: C/D layout col=lane&31, row=(reg&3)+8*(reg>>2)+4*(lane>>5)
  const int ecol = lane & 31;
  const int erow = 4 * (lane >> 5);
#pragma unroll
  for (int mi = 0; mi < 2; ++mi)
#pragma unroll
    for (int ni = 0; ni < 4; ++ni) {
      int col = bx * 256 + wc * 128 + ni * 32 + ecol;
#pragma unroll
      for (int reg = 0; reg < 16; ++reg) {
        int row = by * 128 + wr * 64 + mi * 32 + (reg & 3) + 8 * (reg >> 2) + erow;
        C[(size_t)row * 2048 + col] = acc[mi][ni][reg];
      }
    }
}

// ---------------- row softmax: one wave per row, no LDS, no barriers --------
__global__ __launch_bounds__(256) void softmax_kernel(float* __restrict__ C) {
  const int lane = threadIdx.x & 63;
  const int wv = threadIdx.x >> 6;
  const int row = blockIdx.x * 4 + wv;
  float4* p = (float4*)(C + (size_t)row * MCOLS);

  float4 v[8];
#pragma unroll
  for (int j = 0; j < 8; ++j) v[j] = p[j * 64 + lane];

  float vmax = -3.4e38f;
#pragma unroll
  for (int j = 0; j < 8; ++j)
    vmax = fmaxf(vmax, fmaxf(fmaxf(v[j].x, v[j].y), fmaxf(v[j].z, v[j].w)));
#pragma unroll
  for (int off = 32; off > 0; off >>= 1)
    vmax = fmaxf(vmax, __shfl_xor(vmax, off));

  float sum = 0.f;
#pragma unroll
  for (int j = 0; j < 8; ++j) {
    v[j].x = __expf(v[j].x - vmax);
    v[j].y = __expf(v[j].y - vmax);
    v[j].z = __expf(v[j].z - vmax);
    v[j].w = __expf(v[j].w - vmax);
    sum += (v[j].x + v[j].y) + (v[j].z + v[j].w);
  }
#pragma unroll
  for (int off = 32; off > 0; off >>= 1)
    sum += __shfl_xor(sum, off);
  float inv = 1.0f / sum;

#pragma unroll
  for (int j = 0; j < 8; ++j) {
    v[j].x *= inv; v[j].y *= inv; v[j].z *= inv; v[j].w *= inv;
    p[j * 64 + lane] = v[j];
  }
}

// ---------------- launcher --------------------------------------------------
extern "C" void kernel_launch(void* const* d_in, const int* in_sizes, int n_in,
                              void* d_out, int out_size, void* d_ws, size_t ws_size,
                              hipStream_t stream) {
  const float* X      = (const float*)d_in[0];
  const float* weight = (const float*)d_in[1];
  const float* W1     = (const float*)d_in[2];
  const float* b1     = (const float*)d_in[3];
  const float* W2     = (const float*)d_in[4];
  const float* b2     = (const float*)d_in[5];
  const float* W3     = (const float*)d_in[6];
  const float* b3     = (const float*)d_in[7];
  float* out = (float*)d_out;

  const int N = 2048, M = 2048;
  const int Bdim = in_sizes[0] / N;   // 8192

  float* rowS = (float*)d_ws;
  float* part = rowS + 2048;
  unsigned short* Xh  = (unsigned short*)(part + NCHUNK * 2048);
  unsigned short* Xl  = Xh + (size_t)Bdim * N;
  unsigned short* Bth = Xl + (size_t)Bdim * N;
  unsigned short* Btl = Bth + (size_t)M * N;

  const int conv_blocks = (Bdim * N) / 4 / 256;  // 16384
  pre_kernel<<<CS_BLOCKS + RS_BLOCKS + conv_blocks, 256, 0, stream>>>(
      X, weight, Xh, Xl, part, rowS);

  nca_update_kernel<<<dim3(M / 32, N / 32), 256, 0, stream>>>(
      weight, part, rowS, W1, b1, W2, b2, W3, b3, Bth, Btl);

  gemm_kernel<<<dim3(M / 256, Bdim / 128), 256, 0, stream>>>(Xh, Xl, Bth, Btl, out);

  softmax_kernel<<<Bdim / 4, 256, 0, stream>>>(out);
}

// Round 9
// 331.482 us; speedup vs baseline: 1.2495x; 1.2495x over previous
//
#include <hip/hip_runtime.h>
#include <hip/hip_bf16.h>

// B=8192, N=M=K=2048, H=10.
// Pipeline (5 launches):
//   1) pre_kernel: [col-sum partials] + [row sums of W] + [X -> per-row-scaled
//      2-level int8 split X1,X2 + sx1 row scales]
//   2) nca_update: finish col sums, per-cell MLP, write Wt = new_weight^T (fp32)
//   3) bquant: per-row (=Wn column) 2-level int8 quantize of Wt -> B1,B2,sw1
//   4) i8 MFMA GEMM (32x32x32), R5 structure/swizzle, BK=64, 3 exact i8 terms:
//      logits = s1x[r]*s1w[c]*(X1W1 + (X1W2+X2W1)/254); epilogue applies sw1,
//      softmax applies sx1.
//   5) row softmax (one wave/row), applying sx1[row] on load.

typedef int int4v __attribute__((ext_vector_type(4)));
typedef int int16v __attribute__((ext_vector_type(16)));

#define GK 2048
#define NROWS 2048
#define MCOLS 2048
#define NCHUNK 16

// ---------------- fused pre-pass --------------------------------------------
// blocks [0,128): col-sum partials; [128, 128+2048): W row sums;
// [2176, 2176+8192): X row quantize (2-level i8, per-row scale)
#define CS_BLOCKS 128
#define RS_BLOCKS 2048
__global__ __launch_bounds__(256) void pre_kernel(
    const float* __restrict__ X, const float* __restrict__ W,
    signed char* __restrict__ X1, signed char* __restrict__ X2,
    float* __restrict__ sx1,
    float* __restrict__ part, float* __restrict__ rowS) {
  const int bid = blockIdx.x;
  const int tid = threadIdx.x;

  if (bid < CS_BLOCKS) {
    int chunk = bid >> 3;                 // 0..15
    int j = (bid & 7) * 256 + tid;        // column
    int i0 = chunk * (NROWS / NCHUNK);
    float s = 0.f;
    for (int i = i0; i < i0 + NROWS / NCHUNK; ++i) s += W[(size_t)i * MCOLS + j];
    part[(size_t)chunk * MCOLS + j] = s;
    return;
  }
  if (bid < CS_BLOCKS + RS_BLOCKS) {
    int row = bid - CS_BLOCKS;
    const float4* p = (const float4*)(W + (size_t)row * MCOLS);
    float4 a = p[tid];
    float4 b = p[tid + 256];
    float v = (a.x + a.y) + (a.z + a.w) + (b.x + b.y) + (b.z + b.w);
    __shared__ float red[256];
    red[tid] = v;
    __syncthreads();
    for (int s = 128; s > 0; s >>= 1) {
      if (tid < s) red[tid] += red[tid + s];
      __syncthreads();
    }
    if (tid == 0) rowS[row] = red[0];
    return;
  }
  // X row quantization: one block per row, 8 elems/thread
  {
    int row = bid - CS_BLOCKS - RS_BLOCKS;
    const float4* xr = (const float4*)(X + (size_t)row * GK);
    float4 a = xr[tid * 2];
    float4 b = xr[tid * 2 + 1];
    float xs[8] = {a.x, a.y, a.z, a.w, b.x, b.y, b.z, b.w};
    float am = 0.f;
#pragma unroll
    for (int i = 0; i < 8; ++i) am = fmaxf(am, fabsf(xs[i]));
    const int lane = tid & 63, wv = tid >> 6;
#pragma unroll
    for (int off = 32; off > 0; off >>= 1)
      am = fmaxf(am, __shfl_xor(am, off));
    __shared__ float wred[4];
    if (lane == 0) wred[wv] = am;
    __syncthreads();
    float amax = fmaxf(fmaxf(wred[0], wred[1]), fmaxf(wred[2], wred[3]));
    float s1 = amax * (1.0f / 127.0f);
    float inv = 127.0f / amax;
    int q1[8], q2[8];
#pragma unroll
    for (int i = 0; i < 8; ++i) {
      q1[i] = (int)rintf(xs[i] * inv);
      float r = xs[i] - (float)q1[i] * s1;
      q2[i] = (int)rintf(r * (254.0f * inv));
    }
    unsigned lo1 = (q1[0] & 255) | ((q1[1] & 255) << 8) | ((q1[2] & 255) << 16) | ((q1[3] & 255) << 24);
    unsigned hi1 = (q1[4] & 255) | ((q1[5] & 255) << 8) | ((q1[6] & 255) << 16) | ((q1[7] & 255) << 24);
    unsigned lo2 = (q2[0] & 255) | ((q2[1] & 255) << 8) | ((q2[2] & 255) << 16) | ((q2[3] & 255) << 24);
    unsigned hi2 = (q2[4] & 255) | ((q2[5] & 255) << 8) | ((q2[6] & 255) << 16) | ((q2[7] & 255) << 24);
    ((uint2*)(X1 + (size_t)row * GK))[tid] = make_uint2(lo1, hi1);
    ((uint2*)(X2 + (size_t)row * GK))[tid] = make_uint2(lo2, hi2);
    if (tid == 0) sx1[row] = s1;
  }
}

// ------- NCA MLP -> new_weight, transposed fp32 out -------------------------
__global__ __launch_bounds__(256) void nca_update_kernel(
    const float* __restrict__ W, const float* __restrict__ part,
    const float* __restrict__ rowS,
    const float* __restrict__ W1, const float* __restrict__ b1,
    const float* __restrict__ W2, const float* __restrict__ b2,
    const float* __restrict__ W3, const float* __restrict__ b3,
    float* __restrict__ Wt) {
  __shared__ float sW1[30], sb1[10], sW2[100], sb2[10], sW3[10], sb3;
  __shared__ float sColS[32];
  __shared__ float cred[NCHUNK][33];
  __shared__ float Tf[32][33];
  const int tid = threadIdx.x;
  const int i0 = blockIdx.y * 32;
  const int j0 = blockIdx.x * 32;

  if (tid < 30) sW1[tid] = W1[tid];
  if (tid < 10) { sb1[tid] = b1[tid]; sb2[tid] = b2[tid]; sW3[tid] = W3[tid]; }
  if (tid >= 32 && tid < 132) sW2[tid - 32] = W2[tid - 32];
  if (tid == 0) sb3 = b3[0];

  {
    int ch = tid >> 5;
    int jl = tid & 31;
    cred[ch][jl]     = part[(size_t)ch * MCOLS + j0 + jl];
    cred[ch + 8][jl] = part[(size_t)(ch + 8) * MCOLS + j0 + jl];
  }
  __syncthreads();
  if (tid < 32) {
    float s = 0.f;
#pragma unroll
    for (int c = 0; c < NCHUNK; ++c) s += cred[c][tid];
    sColS[tid] = s;
  }
  __syncthreads();

  const int r = tid >> 5;
  const int c = tid & 31;

  float w[4], fwd[4], bwd[4];
#pragma unroll
  for (int cell = 0; cell < 4; ++cell) {
    int il = r + 8 * cell;
    float wv = W[(size_t)(i0 + il) * MCOLS + j0 + c];
    w[cell] = wv;
    fwd[cell] = (sColS[c] - wv) * (1.0f / (float)(NROWS - 1));
    bwd[cell] = (rowS[i0 + il] - wv) * (1.0f / (float)(MCOLS - 1));
  }

  float h1[4][10];
#pragma unroll
  for (int o = 0; o < 10; ++o) {
    float w1a = sW1[o], w1b = sW1[10 + o], w1c = sW1[20 + o], bb = sb1[o];
#pragma unroll
    for (int cell = 0; cell < 4; ++cell) {
      float v = fmaf(w[cell], w1a, fmaf(fwd[cell], w1b, fmaf(bwd[cell], w1c, bb)));
      h1[cell][o] = fmaxf(v, 0.f);
    }
  }
  float u[4] = {sb3, sb3, sb3, sb3};
#pragma unroll
  for (int o = 0; o < 10; ++o) {
    float h2[4];
    float bb = sb2[o];
#pragma unroll
    for (int cell = 0; cell < 4; ++cell) h2[cell] = bb;
#pragma unroll
    for (int p = 0; p < 10; ++p) {
      float wv = sW2[p * 10 + o];
#pragma unroll
      for (int cell = 0; cell < 4; ++cell) h2[cell] = fmaf(h1[cell][p], wv, h2[cell]);
    }
    float w3 = sW3[o];
#pragma unroll
    for (int cell = 0; cell < 4; ++cell) u[cell] = fmaf(fmaxf(h2[cell], 0.f), w3, u[cell]);
  }

#pragma unroll
  for (int cell = 0; cell < 4; ++cell) {
    int il = r + 8 * cell;
    Tf[il][c] = w[cell] + u[cell];
  }
  __syncthreads();

  // transposed write: Wt[j][i], float2-vectorized
  {
    int r2 = tid >> 4;          // 0..15
    int ic = (tid & 15) * 2;    // 0..30
#pragma unroll
    for (int half = 0; half < 2; ++half) {
      int jl = r2 + 16 * half;
      float2 v = make_float2(Tf[ic][jl], Tf[ic + 1][jl]);
      *(float2*)(&Wt[(size_t)(j0 + jl) * NROWS + i0 + ic]) = v;
    }
  }
}

// -------- B quantize: one block per Wt row (= Wn column) --------------------
__global__ __launch_bounds__(256) void bquant_kernel(
    const float* __restrict__ Wt, signed char* __restrict__ B1,
    signed char* __restrict__ B2, float* __restrict__ sw1) {
  const int row = blockIdx.x;
  const int tid = threadIdx.x;
  const float4* wr = (const float4*)(Wt + (size_t)row * GK);
  float4 a = wr[tid * 2];
  float4 b = wr[tid * 2 + 1];
  float xs[8] = {a.x, a.y, a.z, a.w, b.x, b.y, b.z, b.w};
  float am = 0.f;
#pragma unroll
  for (int i = 0; i < 8; ++i) am = fmaxf(am, fabsf(xs[i]));
  const int lane = tid & 63, wv = tid >> 6;
#pragma unroll
  for (int off = 32; off > 0; off >>= 1)
    am = fmaxf(am, __shfl_xor(am, off));
  __shared__ float wred[4];
  if (lane == 0) wred[wv] = am;
  __syncthreads();
  float amax = fmaxf(fmaxf(wred[0], wred[1]), fmaxf(wred[2], wred[3]));
  float s1 = amax * (1.0f / 127.0f);
  float inv = 127.0f / amax;
  int q1[8], q2[8];
#pragma unroll
  for (int i = 0; i < 8; ++i) {
    q1[i] = (int)rintf(xs[i] * inv);
    float r = xs[i] - (float)q1[i] * s1;
    q2[i] = (int)rintf(r * (254.0f * inv));
  }
  unsigned lo1 = (q1[0] & 255) | ((q1[1] & 255) << 8) | ((q1[2] & 255) << 16) | ((q1[3] & 255) << 24);
  unsigned hi1 = (q1[4] & 255) | ((q1[5] & 255) << 8) | ((q1[6] & 255) << 16) | ((q1[7] & 255) << 24);
  unsigned lo2 = (q2[0] & 255) | ((q2[1] & 255) << 8) | ((q2[2] & 255) << 16) | ((q2[3] & 255) << 24);
  unsigned hi2 = (q2[4] & 255) | ((q2[5] & 255) << 8) | ((q2[6] & 255) << 16) | ((q2[7] & 255) << 24);
  ((uint2*)(B1 + (size_t)row * GK))[tid] = make_uint2(lo1, hi1);
  ((uint2*)(B2 + (size_t)row * GK))[tid] = make_uint2(lo2, hi2);
  if (tid == 0) sw1[row] = s1;
}

// ---------------- 2-level i8 MFMA GEMM (R5 structure, 32x32x32) -------------
// BK=64 (bytes). LDS 16-row blocks of 1KB; slot s holds (row=s>>2,
// chunk=(s&3)^((s>>3)&3)); staging lane l fetches row l>>2, chunk
// (l&3)^((l>>3)&3) -> quad = contiguous 64B. Frag read (row rl, chunk c):
// slot = 4*rl + (c ^ ((rl>>1)&3)) -> 2-way max (free).
// i8 32x32x32 A-frag: lane l holds A[m=l&31][k=(l>>5)*16 + j], j=0..15 (16B).
__global__ __launch_bounds__(256) void gemm_kernel(
    const signed char* __restrict__ X1, const signed char* __restrict__ X2,
    const signed char* __restrict__ B1, const signed char* __restrict__ B2,
    const float* __restrict__ sw1, float* __restrict__ C) {
  __shared__ __align__(16) char sL[32768];  // A1@0 A2@8K B1@16K B2@24K

  const int tid = threadIdx.x;
  const int lane = tid & 63;
  const int wave = tid >> 6;
  const int wr = wave >> 1;
  const int wc = wave & 1;

  const int bx = blockIdx.x;
  const int by = blockIdx.y;

  const signed char* A1g = X1 + (size_t)(by * 128) * GK;
  const signed char* A2g = X2 + (size_t)(by * 128) * GK;
  const signed char* B1g = B1 + (size_t)(bx * 128) * GK;
  const signed char* B2g = B2 + (size_t)(bx * 128) * GK;

  const int srow = lane >> 2;
  const int skof = ((lane & 3) ^ ((lane >> 3) & 3)) * 16;  // bytes

  const int rl = lane & 15;
  const int fhalf = (lane >> 4) & 1;
  const int fck = lane >> 5;            // 16B sub-chunk within K=32

  int16v acc_h[2][2], acc_c[2][2];
#pragma unroll
  for (int i = 0; i < 2; ++i)
#pragma unroll
    for (int j = 0; j < 2; ++j)
#pragma unroll
      for (int e = 0; e < 16; ++e) { acc_h[i][j][e] = 0; acc_c[i][j][e] = 0; }

  for (int k0 = 0; k0 < GK; k0 += 64) {
#pragma unroll
    for (int r = 0; r < 2; ++r) {
      int R = wave * 2 + r;                       // 16-row block 0..7
      size_t goff = (size_t)(R * 16 + srow) * GK + k0 + skof;
      int ldsoff = R * 1024;                      // bytes
      __builtin_amdgcn_global_load_lds(
          (const __attribute__((address_space(1))) void*)(A1g + goff),
          (__attribute__((address_space(3))) void*)(sL + ldsoff), 16, 0, 0);
      __builtin_amdgcn_global_load_lds(
          (const __attribute__((address_space(1))) void*)(A2g + goff),
          (__attribute__((address_space(3))) void*)(sL + 8192 + ldsoff), 16, 0, 0);
      __builtin_amdgcn_global_load_lds(
          (const __attribute__((address_space(1))) void*)(B1g + goff),
          (__attribute__((address_space(3))) void*)(sL + 16384 + ldsoff), 16, 0, 0);
      __builtin_amdgcn_global_load_lds(
          (const __attribute__((address_space(1))) void*)(B2g + goff),
          (__attribute__((address_space(3))) void*)(sL + 24576 + ldsoff), 16, 0, 0);
    }
    __syncthreads();

    int4v a1[2][2], a2[2][2], b1[2][2], b2[2][2];  // [tile][ks]
#pragma unroll
    for (int mi = 0; mi < 2; ++mi)
#pragma unroll
      for (int ks = 0; ks < 2; ++ks) {
        int R = wr * 4 + mi * 2 + fhalf;
        int c = 2 * ks + fck;
        int slot = 4 * rl + (c ^ ((rl >> 1) & 3));
        int off = R * 1024 + slot * 16;
        a1[mi][ks] = *(const int4v*)(sL + off);
        a2[mi][ks] = *(const int4v*)(sL + 8192 + off);
      }
#pragma unroll
    for (int ni = 0; ni < 2; ++ni)
#pragma unroll
      for (int ks = 0; ks < 2; ++ks) {
        int R = wc * 4 + ni * 2 + fhalf;
        int c = 2 * ks + fck;
        int slot = 4 * rl + (c ^ ((rl >> 1) & 3));
        int off = R * 1024 + slot * 16;
        b1[ni][ks] = *(const int4v*)(sL + 16384 + off);
        b2[ni][ks] = *(const int4v*)(sL + 24576 + off);
      }
#pragma unroll
    for (int mi = 0; mi < 2; ++mi)
#pragma unroll
      for (int ni = 0; ni < 2; ++ni)
#pragma unroll
        for (int ks = 0; ks < 2; ++ks) {
          acc_h[mi][ni] = __builtin_amdgcn_mfma_i32_32x32x32_i8(a1[mi][ks], b1[ni][ks], acc_h[mi][ni], 0, 0, 0);
          acc_c[mi][ni] = __builtin_amdgcn_mfma_i32_32x32x32_i8(a1[mi][ks], b2[ni][ks], acc_c[mi][ni], 0, 0, 0);
          acc_c[mi][ni] = __builtin_amdgcn_mfma_i32_32x32x32_i8(a2[mi][ks], b1[ni][ks], acc_c[mi][ni], 0, 0, 0);
        }
    __syncthreads();
  }

  // epilogue: C/D col=lane&31, row=(reg&3)+8*(reg>>2)+4*(lane>>5); apply sw1
  const int ecol = lane & 31;
  const int erow = 4 * (lane >> 5);
#pragma unroll
  for (int ni = 0; ni < 2; ++ni) {
    int col = bx * 128 + wc * 64 + ni * 32 + ecol;
    float sw = sw1[col];
#pragma unroll
    for (int mi = 0; mi < 2; ++mi) {
#pragma unroll
      for (int reg = 0; reg < 16; ++reg) {
        int row = by * 128 + wr * 64 + mi * 32 + (reg & 3) + 8 * (reg >> 2) + erow;
        float v = (float)acc_h[mi][ni][reg] + (float)acc_c[mi][ni][reg] * (1.0f / 254.0f);
        C[(size_t)row * 2048 + col] = v * sw;
      }
    }
  }
}

// ---------------- row softmax: one wave per row, applies sx1[row] -----------
__global__ __launch_bounds__(256) void softmax_kernel(
    float* __restrict__ C, const float* __restrict__ sx1) {
  const int lane = threadIdx.x & 63;
  const int wv = threadIdx.x >> 6;
  const int row = blockIdx.x * 4 + wv;
  const float sx = sx1[row];
  float4* p = (float4*)(C + (size_t)row * MCOLS);

  float4 v[8];
#pragma unroll
  for (int j = 0; j < 8; ++j) {
    v[j] = p[j * 64 + lane];
    v[j].x *= sx; v[j].y *= sx; v[j].z *= sx; v[j].w *= sx;
  }

  float vmax = -3.4e38f;
#pragma unroll
  for (int j = 0; j < 8; ++j)
    vmax = fmaxf(vmax, fmaxf(fmaxf(v[j].x, v[j].y), fmaxf(v[j].z, v[j].w)));
#pragma unroll
  for (int off = 32; off > 0; off >>= 1)
    vmax = fmaxf(vmax, __shfl_xor(vmax, off));

  float sum = 0.f;
#pragma unroll
  for (int j = 0; j < 8; ++j) {
    v[j].x = __expf(v[j].x - vmax);
    v[j].y = __expf(v[j].y - vmax);
    v[j].z = __expf(v[j].z - vmax);
    v[j].w = __expf(v[j].w - vmax);
    sum += (v[j].x + v[j].y) + (v[j].z + v[j].w);
  }
#pragma unroll
  for (int off = 32; off > 0; off >>= 1)
    sum += __shfl_xor(sum, off);
  float inv = 1.0f / sum;

#pragma unroll
  for (int j = 0; j < 8; ++j) {
    v[j].x *= inv; v[j].y *= inv; v[j].z *= inv; v[j].w *= inv;
    p[j * 64 + lane] = v[j];
  }
}

// ---------------- launcher --------------------------------------------------
extern "C" void kernel_launch(void* const* d_in, const int* in_sizes, int n_in,
                              void* d_out, int out_size, void* d_ws, size_t ws_size,
                              hipStream_t stream) {
  const float* X      = (const float*)d_in[0];
  const float* weight = (const float*)d_in[1];
  const float* W1     = (const float*)d_in[2];
  const float* b1     = (const float*)d_in[3];
  const float* W2     = (const float*)d_in[4];
  const float* b2     = (const float*)d_in[5];
  const float* W3     = (const float*)d_in[6];
  const float* b3     = (const float*)d_in[7];
  float* out = (float*)d_out;

  const int N = 2048, M = 2048;
  const int Bdim = in_sizes[0] / N;   // 8192

  // workspace (floats first): rowS[2048] part[16*2048] sx1[8192] sw1[2048]
  // Wt[2048*2048] | then bytes: X1,X2 [B*N] B1,B2 [M*N]
  float* rowS = (float*)d_ws;
  float* part = rowS + 2048;
  float* sx1  = part + NCHUNK * 2048;
  float* sw1  = sx1 + 8192;
  float* Wt   = sw1 + 2048;
  signed char* X1 = (signed char*)(Wt + (size_t)M * N);
  signed char* X2 = X1 + (size_t)Bdim * N;
  signed char* B1q = X2 + (size_t)Bdim * N;
  signed char* B2q = B1q + (size_t)M * N;

  pre_kernel<<<CS_BLOCKS + RS_BLOCKS + Bdim, 256, 0, stream>>>(
      X, weight, X1, X2, sx1, part, rowS);

  nca_update_kernel<<<dim3(M / 32, N / 32), 256, 0, stream>>>(
      weight, part, rowS, W1, b1, W2, b2, W3, b3, Wt);

  bquant_kernel<<<M, 256, 0, stream>>>(Wt, B1q, B2q, sw1);

  gemm_kernel<<<dim3(M / 128, Bdim / 128), 256, 0, stream>>>(
      X1, X2, B1q, B2q, sw1, out);

  softmax_kernel<<<Bdim / 4, 256, 0, stream>>>(out, sx1);
}

// Round 10
// 290.187 us; speedup vs baseline: 1.4273x; 1.1423x over previous
//
#include <hip/hip_runtime.h>
#include <hip/hip_bf16.h>

// B=8192, N=M=K=2048, H=10.
// Pipeline (5 launches):
//   1) pre_kernel: [col-sum partials] + [row sums of W] + [X -> per-row-scaled
//      2-level int8 split X1,X2 + sx1 row scales]
//   2) nca_update: finish col sums, per-cell MLP, write Wt = new_weight^T (fp32)
//   3) bquant: per-row (=Wn column) 2-level int8 quantize of Wt -> B1,B2,sw1
//   4) i8 MFMA GEMM (32x32x32), BK=64, 3 exact i8 terms; REGISTER-DIETED:
//      B-frags loaded inside the (ni,ks) loop, __launch_bounds__(256,2) so
//      unified regs (128 AGPR acc + ~90 VGPR) fit 2 waves/SIMD.
//   5) row softmax (one wave/row), applying sx1[row] on load.

typedef int int4v __attribute__((ext_vector_type(4)));
typedef int int16v __attribute__((ext_vector_type(16)));

#define GK 2048
#define NROWS 2048
#define MCOLS 2048
#define NCHUNK 16

// ---------------- fused pre-pass --------------------------------------------
#define CS_BLOCKS 128
#define RS_BLOCKS 2048
__global__ __launch_bounds__(256) void pre_kernel(
    const float* __restrict__ X, const float* __restrict__ W,
    signed char* __restrict__ X1, signed char* __restrict__ X2,
    float* __restrict__ sx1,
    float* __restrict__ part, float* __restrict__ rowS) {
  const int bid = blockIdx.x;
  const int tid = threadIdx.x;

  if (bid < CS_BLOCKS) {
    int chunk = bid >> 3;                 // 0..15
    int j = (bid & 7) * 256 + tid;        // column
    int i0 = chunk * (NROWS / NCHUNK);
    float s = 0.f;
    for (int i = i0; i < i0 + NROWS / NCHUNK; ++i) s += W[(size_t)i * MCOLS + j];
    part[(size_t)chunk * MCOLS + j] = s;
    return;
  }
  if (bid < CS_BLOCKS + RS_BLOCKS) {
    int row = bid - CS_BLOCKS;
    const float4* p = (const float4*)(W + (size_t)row * MCOLS);
    float4 a = p[tid];
    float4 b = p[tid + 256];
    float v = (a.x + a.y) + (a.z + a.w) + (b.x + b.y) + (b.z + b.w);
    __shared__ float red[256];
    red[tid] = v;
    __syncthreads();
    for (int s = 128; s > 0; s >>= 1) {
      if (tid < s) red[tid] += red[tid + s];
      __syncthreads();
    }
    if (tid == 0) rowS[row] = red[0];
    return;
  }
  // X row quantization: one block per row, 8 elems/thread
  {
    int row = bid - CS_BLOCKS - RS_BLOCKS;
    const float4* xr = (const float4*)(X + (size_t)row * GK);
    float4 a = xr[tid * 2];
    float4 b = xr[tid * 2 + 1];
    float xs[8] = {a.x, a.y, a.z, a.w, b.x, b.y, b.z, b.w};
    float am = 0.f;
#pragma unroll
    for (int i = 0; i < 8; ++i) am = fmaxf(am, fabsf(xs[i]));
    const int lane = tid & 63, wv = tid >> 6;
#pragma unroll
    for (int off = 32; off > 0; off >>= 1)
      am = fmaxf(am, __shfl_xor(am, off));
    __shared__ float wred[4];
    if (lane == 0) wred[wv] = am;
    __syncthreads();
    float amax = fmaxf(fmaxf(wred[0], wred[1]), fmaxf(wred[2], wred[3]));
    float s1 = amax * (1.0f / 127.0f);
    float inv = 127.0f / amax;
    int q1[8], q2[8];
#pragma unroll
    for (int i = 0; i < 8; ++i) {
      q1[i] = (int)rintf(xs[i] * inv);
      float r = xs[i] - (float)q1[i] * s1;
      q2[i] = (int)rintf(r * (254.0f * inv));
    }
    unsigned lo1 = (q1[0] & 255) | ((q1[1] & 255) << 8) | ((q1[2] & 255) << 16) | ((q1[3] & 255) << 24);
    unsigned hi1 = (q1[4] & 255) | ((q1[5] & 255) << 8) | ((q1[6] & 255) << 16) | ((q1[7] & 255) << 24);
    unsigned lo2 = (q2[0] & 255) | ((q2[1] & 255) << 8) | ((q2[2] & 255) << 16) | ((q2[3] & 255) << 24);
    unsigned hi2 = (q2[4] & 255) | ((q2[5] & 255) << 8) | ((q2[6] & 255) << 16) | ((q2[7] & 255) << 24);
    ((uint2*)(X1 + (size_t)row * GK))[tid] = make_uint2(lo1, hi1);
    ((uint2*)(X2 + (size_t)row * GK))[tid] = make_uint2(lo2, hi2);
    if (tid == 0) sx1[row] = s1;
  }
}

// ------- NCA MLP -> new_weight, transposed fp32 out -------------------------
__global__ __launch_bounds__(256) void nca_update_kernel(
    const float* __restrict__ W, const float* __restrict__ part,
    const float* __restrict__ rowS,
    const float* __restrict__ W1, const float* __restrict__ b1,
    const float* __restrict__ W2, const float* __restrict__ b2,
    const float* __restrict__ W3, const float* __restrict__ b3,
    float* __restrict__ Wt) {
  __shared__ float sW1[30], sb1[10], sW2[100], sb2[10], sW3[10], sb3;
  __shared__ float sColS[32];
  __shared__ float cred[NCHUNK][33];
  __shared__ float Tf[32][33];
  const int tid = threadIdx.x;
  const int i0 = blockIdx.y * 32;
  const int j0 = blockIdx.x * 32;

  if (tid < 30) sW1[tid] = W1[tid];
  if (tid < 10) { sb1[tid] = b1[tid]; sb2[tid] = b2[tid]; sW3[tid] = W3[tid]; }
  if (tid >= 32 && tid < 132) sW2[tid - 32] = W2[tid - 32];
  if (tid == 0) sb3 = b3[0];

  {
    int ch = tid >> 5;
    int jl = tid & 31;
    cred[ch][jl]     = part[(size_t)ch * MCOLS + j0 + jl];
    cred[ch + 8][jl] = part[(size_t)(ch + 8) * MCOLS + j0 + jl];
  }
  __syncthreads();
  if (tid < 32) {
    float s = 0.f;
#pragma unroll
    for (int c = 0; c < NCHUNK; ++c) s += cred[c][tid];
    sColS[tid] = s;
  }
  __syncthreads();

  const int r = tid >> 5;
  const int c = tid & 31;

  float w[4], fwd[4], bwd[4];
#pragma unroll
  for (int cell = 0; cell < 4; ++cell) {
    int il = r + 8 * cell;
    float wv = W[(size_t)(i0 + il) * MCOLS + j0 + c];
    w[cell] = wv;
    fwd[cell] = (sColS[c] - wv) * (1.0f / (float)(NROWS - 1));
    bwd[cell] = (rowS[i0 + il] - wv) * (1.0f / (float)(MCOLS - 1));
  }

  float h1[4][10];
#pragma unroll
  for (int o = 0; o < 10; ++o) {
    float w1a = sW1[o], w1b = sW1[10 + o], w1c = sW1[20 + o], bb = sb1[o];
#pragma unroll
    for (int cell = 0; cell < 4; ++cell) {
      float v = fmaf(w[cell], w1a, fmaf(fwd[cell], w1b, fmaf(bwd[cell], w1c, bb)));
      h1[cell][o] = fmaxf(v, 0.f);
    }
  }
  float u[4] = {sb3, sb3, sb3, sb3};
#pragma unroll
  for (int o = 0; o < 10; ++o) {
    float h2[4];
    float bb = sb2[o];
#pragma unroll
    for (int cell = 0; cell < 4; ++cell) h2[cell] = bb;
#pragma unroll
    for (int p = 0; p < 10; ++p) {
      float wv = sW2[p * 10 + o];
#pragma unroll
      for (int cell = 0; cell < 4; ++cell) h2[cell] = fmaf(h1[cell][p], wv, h2[cell]);
    }
    float w3 = sW3[o];
#pragma unroll
    for (int cell = 0; cell < 4; ++cell) u[cell] = fmaf(fmaxf(h2[cell], 0.f), w3, u[cell]);
  }

#pragma unroll
  for (int cell = 0; cell < 4; ++cell) {
    int il = r + 8 * cell;
    Tf[il][c] = w[cell] + u[cell];
  }
  __syncthreads();

  {
    int r2 = tid >> 4;          // 0..15
    int ic = (tid & 15) * 2;    // 0..30
#pragma unroll
    for (int half = 0; half < 2; ++half) {
      int jl = r2 + 16 * half;
      float2 v = make_float2(Tf[ic][jl], Tf[ic + 1][jl]);
      *(float2*)(&Wt[(size_t)(j0 + jl) * NROWS + i0 + ic]) = v;
    }
  }
}

// -------- B quantize: one block per Wt row (= Wn column) --------------------
__global__ __launch_bounds__(256) void bquant_kernel(
    const float* __restrict__ Wt, signed char* __restrict__ B1,
    signed char* __restrict__ B2, float* __restrict__ sw1) {
  const int row = blockIdx.x;
  const int tid = threadIdx.x;
  const float4* wr = (const float4*)(Wt + (size_t)row * GK);
  float4 a = wr[tid * 2];
  float4 b = wr[tid * 2 + 1];
  float xs[8] = {a.x, a.y, a.z, a.w, b.x, b.y, b.z, b.w};
  float am = 0.f;
#pragma unroll
  for (int i = 0; i < 8; ++i) am = fmaxf(am, fabsf(xs[i]));
  const int lane = tid & 63, wv = tid >> 6;
#pragma unroll
  for (int off = 32; off > 0; off >>= 1)
    am = fmaxf(am, __shfl_xor(am, off));
  __shared__ float wred[4];
  if (lane == 0) wred[wv] = am;
  __syncthreads();
  float amax = fmaxf(fmaxf(wred[0], wred[1]), fmaxf(wred[2], wred[3]));
  float s1 = amax * (1.0f / 127.0f);
  float inv = 127.0f / amax;
  int q1[8], q2[8];
#pragma unroll
  for (int i = 0; i < 8; ++i) {
    q1[i] = (int)rintf(xs[i] * inv);
    float r = xs[i] - (float)q1[i] * s1;
    q2[i] = (int)rintf(r * (254.0f * inv));
  }
  unsigned lo1 = (q1[0] & 255) | ((q1[1] & 255) << 8) | ((q1[2] & 255) << 16) | ((q1[3] & 255) << 24);
  unsigned hi1 = (q1[4] & 255) | ((q1[5] & 255) << 8) | ((q1[6] & 255) << 16) | ((q1[7] & 255) << 24);
  unsigned lo2 = (q2[0] & 255) | ((q2[1] & 255) << 8) | ((q2[2] & 255) << 16) | ((q2[3] & 255) << 24);
  unsigned hi2 = (q2[4] & 255) | ((q2[5] & 255) << 8) | ((q2[6] & 255) << 16) | ((q2[7] & 255) << 24);
  ((uint2*)(B1 + (size_t)row * GK))[tid] = make_uint2(lo1, hi1);
  ((uint2*)(B2 + (size_t)row * GK))[tid] = make_uint2(lo2, hi2);
  if (tid == 0) sw1[row] = s1;
}

// ---------------- 2-level i8 MFMA GEMM (32x32x32, BK=64, reg-dieted) --------
// LDS 16-row blocks of 1KB; slot s holds (row=s>>2, chunk=(s&3)^((s>>3)&3));
// staging lane l fetches row l>>2, chunk (l&3)^((l>>3)&3) -> quad-contiguous
// 64B. Frag read (row rl, chunk c): slot = 4*rl + (c ^ ((rl>>1)&3)).
// i8 32x32x32 A-frag: lane l holds A[m=l&31][k=(l>>5)*16 + j], j=0..15 (16B).
// Register budget: 128 AGPR acc + A-frags(32) + one (ni,ks) B-pair(8) + addr.
__global__ __launch_bounds__(256, 2) void gemm_kernel(
    const signed char* __restrict__ X1, const signed char* __restrict__ X2,
    const signed char* __restrict__ B1, const signed char* __restrict__ B2,
    const float* __restrict__ sw1, float* __restrict__ C) {
  __shared__ __align__(16) char sL[32768];  // A1@0 A2@8K B1@16K B2@24K

  const int tid = threadIdx.x;
  const int lane = tid & 63;
  const int wave = tid >> 6;
  const int wr = wave >> 1;
  const int wc = wave & 1;

  const int bx = blockIdx.x;
  const int by = blockIdx.y;

  const signed char* A1g = X1 + (size_t)(by * 128) * GK;
  const signed char* A2g = X2 + (size_t)(by * 128) * GK;
  const signed char* B1g = B1 + (size_t)(bx * 128) * GK;
  const signed char* B2g = B2 + (size_t)(bx * 128) * GK;

  const int srow = lane >> 2;
  const int skof = ((lane & 3) ^ ((lane >> 3) & 3)) * 16;  // bytes

  const int rl = lane & 15;
  const int fhalf = (lane >> 4) & 1;
  const int fck = lane >> 5;            // 16B sub-chunk within K=32

  // precomputed LDS byte offsets (scalar per lane, loop-invariant)
  int aoff[2][2], boff[2][2];           // [tile][ks]
#pragma unroll
  for (int t = 0; t < 2; ++t)
#pragma unroll
    for (int ks = 0; ks < 2; ++ks) {
      int c = 2 * ks + fck;
      int slot = 4 * rl + (c ^ ((rl >> 1) & 3));
      aoff[t][ks] = (wr * 4 + t * 2 + fhalf) * 1024 + slot * 16;
      boff[t][ks] = (wc * 4 + t * 2 + fhalf) * 1024 + slot * 16;
    }

  int16v acc_h[2][2], acc_c[2][2];
#pragma unroll
  for (int i = 0; i < 2; ++i)
#pragma unroll
    for (int j = 0; j < 2; ++j)
#pragma unroll
      for (int e = 0; e < 16; ++e) { acc_h[i][j][e] = 0; acc_c[i][j][e] = 0; }

  for (int k0 = 0; k0 < GK; k0 += 64) {
#pragma unroll
    for (int r = 0; r < 2; ++r) {
      int R = wave * 2 + r;                       // 16-row block 0..7
      size_t goff = (size_t)(R * 16 + srow) * GK + k0 + skof;
      int ldsoff = R * 1024;                      // bytes
      __builtin_amdgcn_global_load_lds(
          (const __attribute__((address_space(1))) void*)(A1g + goff),
          (__attribute__((address_space(3))) void*)(sL + ldsoff), 16, 0, 0);
      __builtin_amdgcn_global_load_lds(
          (const __attribute__((address_space(1))) void*)(A2g + goff),
          (__attribute__((address_space(3))) void*)(sL + 8192 + ldsoff), 16, 0, 0);
      __builtin_amdgcn_global_load_lds(
          (const __attribute__((address_space(1))) void*)(B1g + goff),
          (__attribute__((address_space(3))) void*)(sL + 16384 + ldsoff), 16, 0, 0);
      __builtin_amdgcn_global_load_lds(
          (const __attribute__((address_space(1))) void*)(B2g + goff),
          (__attribute__((address_space(3))) void*)(sL + 24576 + ldsoff), 16, 0, 0);
    }
    __syncthreads();

    // A-frags stay live (32 VGPRs); B-frags loaded per (ni,ks) (8 VGPRs)
    int4v a1[2][2], a2[2][2];
#pragma unroll
    for (int mi = 0; mi < 2; ++mi)
#pragma unroll
      for (int ks = 0; ks < 2; ++ks) {
        a1[mi][ks] = *(const int4v*)(sL + aoff[mi][ks]);
        a2[mi][ks] = *(const int4v*)(sL + 8192 + aoff[mi][ks]);
      }
#pragma unroll
    for (int ni = 0; ni < 2; ++ni)
#pragma unroll
      for (int ks = 0; ks < 2; ++ks) {
        int4v b1f = *(const int4v*)(sL + 16384 + boff[ni][ks]);
        int4v b2f = *(const int4v*)(sL + 24576 + boff[ni][ks]);
#pragma unroll
        for (int mi = 0; mi < 2; ++mi) {
          acc_h[mi][ni] = __builtin_amdgcn_mfma_i32_32x32x32_i8(a1[mi][ks], b1f, acc_h[mi][ni], 0, 0, 0);
          acc_c[mi][ni] = __builtin_amdgcn_mfma_i32_32x32x32_i8(a1[mi][ks], b2f, acc_c[mi][ni], 0, 0, 0);
          acc_c[mi][ni] = __builtin_amdgcn_mfma_i32_32x32x32_i8(a2[mi][ks], b1f, acc_c[mi][ni], 0, 0, 0);
        }
      }
    __syncthreads();
  }

  // epilogue: C/D col=lane&31, row=(reg&3)+8*(reg>>2)+4*(lane>>5); apply sw1
  const int ecol = lane & 31;
  const int erow = 4 * (lane >> 5);
#pragma unroll
  for (int ni = 0; ni < 2; ++ni) {
    int col = bx * 128 + wc * 64 + ni * 32 + ecol;
    float sw = sw1[col];
#pragma unroll
    for (int mi = 0; mi < 2; ++mi) {
#pragma unroll
      for (int reg = 0; reg < 16; ++reg) {
        int row = by * 128 + wr * 64 + mi * 32 + (reg & 3) + 8 * (reg >> 2) + erow;
        float v = (float)acc_h[mi][ni][reg] + (float)acc_c[mi][ni][reg] * (1.0f / 254.0f);
        C[(size_t)row * 2048 + col] = v * sw;
      }
    }
  }
}

// ---------------- row softmax: one wave per row, applies sx1[row] -----------
__global__ __launch_bounds__(256) void softmax_kernel(
    float* __restrict__ C, const float* __restrict__ sx1) {
  const int lane = threadIdx.x & 63;
  const int wv = threadIdx.x >> 6;
  const int row = blockIdx.x * 4 + wv;
  const float sx = sx1[row];
  float4* p = (float4*)(C + (size_t)row * MCOLS);

  float4 v[8];
#pragma unroll
  for (int j = 0; j < 8; ++j) {
    v[j] = p[j * 64 + lane];
    v[j].x *= sx; v[j].y *= sx; v[j].z *= sx; v[j].w *= sx;
  }

  float vmax = -3.4e38f;
#pragma unroll
  for (int j = 0; j < 8; ++j)
    vmax = fmaxf(vmax, fmaxf(fmaxf(v[j].x, v[j].y), fmaxf(v[j].z, v[j].w)));
#pragma unroll
  for (int off = 32; off > 0; off >>= 1)
    vmax = fmaxf(vmax, __shfl_xor(vmax, off));

  float sum = 0.f;
#pragma unroll
  for (int j = 0; j < 8; ++j) {
    v[j].x = __expf(v[j].x - vmax);
    v[j].y = __expf(v[j].y - vmax);
    v[j].z = __expf(v[j].z - vmax);
    v[j].w = __expf(v[j].w - vmax);
    sum += (v[j].x + v[j].y) + (v[j].z + v[j].w);
  }
#pragma unroll
  for (int off = 32; off > 0; off >>= 1)
    sum += __shfl_xor(sum, off);
  float inv = 1.0f / sum;

#pragma unroll
  for (int j = 0; j < 8; ++j) {
    v[j].x *= inv; v[j].y *= inv; v[j].z *= inv; v[j].w *= inv;
    p[j * 64 + lane] = v[j];
  }
}

// ---------------- launcher --------------------------------------------------
extern "C" void kernel_launch(void* const* d_in, const int* in_sizes, int n_in,
                              void* d_out, int out_size, void* d_ws, size_t ws_size,
                              hipStream_t stream) {
  const float* X      = (const float*)d_in[0];
  const float* weight = (const float*)d_in[1];
  const float* W1     = (const float*)d_in[2];
  const float* b1     = (const float*)d_in[3];
  const float* W2     = (const float*)d_in[4];
  const float* b2     = (const float*)d_in[5];
  const float* W3     = (const float*)d_in[6];
  const float* b3     = (const float*)d_in[7];
  float* out = (float*)d_out;

  const int N = 2048, M = 2048;
  const int Bdim = in_sizes[0] / N;   // 8192

  float* rowS = (float*)d_ws;
  float* part = rowS + 2048;
  float* sx1  = part + NCHUNK * 2048;
  float* sw1  = sx1 + 8192;
  float* Wt   = sw1 + 2048;
  signed char* X1 = (signed char*)(Wt + (size_t)M * N);
  signed char* X2 = X1 + (size_t)Bdim * N;
  signed char* B1q = X2 + (size_t)Bdim * N;
  signed char* B2q = B1q + (size_t)M * N;

  pre_kernel<<<CS_BLOCKS + RS_BLOCKS + Bdim, 256, 0, stream>>>(
      X, weight, X1, X2, sx1, part, rowS);

  nca_update_kernel<<<dim3(M / 32, N / 32), 256, 0, stream>>>(
      weight, part, rowS, W1, b1, W2, b2, W3, b3, Wt);

  bquant_kernel<<<M, 256, 0, stream>>>(Wt, B1q, B2q, sw1);

  gemm_kernel<<<dim3(M / 128, Bdim / 128), 256, 0, stream>>>(
      X1, X2, B1q, B2q, sw1, out);

  softmax_kernel<<<Bdim / 4, 256, 0, stream>>>(out, sx1);
}